// Round 1
// baseline (500.867 us; speedup 1.0000x reference)
//
#include <hip/hip_runtime.h>
#include <hip/hip_bf16.h>
#include <math.h>

typedef unsigned short u16;
typedef short s16x8 __attribute__((ext_vector_type(8)));
typedef unsigned short u16x8 __attribute__((ext_vector_type(8)));
typedef float f32x4 __attribute__((ext_vector_type(4)));

// Problem constants
#define TTOK 2048
#define HDIM 2048
#define ENUM 32
#define IDIM 768
#define KTOP 4

// Workspace layout (bytes)
#define WS_XB   0L                         // u16[2048*2048]  x in bf16       (8 MB)
#define WS_ACT  8388608L                   // u16[8192*768]   act bf16        (12.6 MB)
#define WS_TIDX 20971520L                  // int[8192] topk expert idx
#define WS_TW   (WS_TIDX + 32768L)         // float[8192] topk weights
#define WS_CNT  (WS_TW + 32768L)           // int[32] counts
#define WS_OFFS (WS_CNT + 128L)            // int[33] offsets
#define WS_CUR  (WS_OFFS + 256L)           // int[32] cursors
#define WS_RTOK (WS_CUR + 128L)            // int[8192] row -> token
#define WS_RW   (WS_RTOK + 32768L)         // float[8192] row -> routing weight

__device__ __forceinline__ u16 f2bf(float f) {
  unsigned u = __builtin_bit_cast(unsigned, f);
  unsigned r = (u + 0x7fffu + ((u >> 16) & 1u)) >> 16;
  return (u16)r;
}
__device__ __forceinline__ unsigned pk2(float a, float b) {
  return (unsigned)f2bf(a) | ((unsigned)f2bf(b) << 16);
}

// ---------------- x f32 -> bf16 ----------------
__global__ __launch_bounds__(256) void cvt_x_kernel(const float* __restrict__ x,
                                                    u16* __restrict__ xb) {
  long i = ((long)blockIdx.x * 256 + threadIdx.x) * 8;
  float4 a = *(const float4*)(x + i);
  float4 b = *(const float4*)(x + i + 4);
  uint4 o;
  o.x = pk2(a.x, a.y);
  o.y = pk2(a.z, a.w);
  o.z = pk2(b.x, b.y);
  o.w = pk2(b.z, b.w);
  *(uint4*)(xb + i) = o;
}

// ---------------- router: logits (f32), top-4, weights, histogram ----------------
__global__ __launch_bounds__(256) void router_kernel(const float* __restrict__ x,
                                                     const float* __restrict__ gw,
                                                     int* __restrict__ tidx,
                                                     float* __restrict__ tw,
                                                     int* __restrict__ counts) {
  __shared__ float xs[HDIM];
  __shared__ float part[256];
  __shared__ float lg[ENUM];
  int t = blockIdx.x;
  const float4* xr = (const float4*)(x + (long)t * HDIM);
  float4* xs4 = (float4*)xs;
  for (int i = threadIdx.x; i < HDIM / 4; i += 256) xs4[i] = xr[i];
  __syncthreads();
  int e = threadIdx.x >> 3, ch = threadIdx.x & 7;
  const float4* gp = (const float4*)(gw + (long)e * HDIM + ch * 256);
  const float4* xp = (const float4*)(xs + ch * 256);
  float s = 0.f;
#pragma unroll 8
  for (int c = 0; c < 64; c++) {
    float4 gv = gp[c], xv = xp[c];
    s += gv.x * xv.x + gv.y * xv.y + gv.z * xv.z + gv.w * xv.w;
  }
  part[threadIdx.x] = s;
  __syncthreads();
  if (threadIdx.x < 32) {
    float v = 0.f;
#pragma unroll
    for (int j = 0; j < 8; j++) v += part[threadIdx.x * 8 + j];
    lg[threadIdx.x] = v;
  }
  __syncthreads();
  if (threadIdx.x == 0) {
    int sel[KTOP]; float sv[KTOP];
    unsigned mask = 0;
    for (int k = 0; k < KTOP; k++) {
      float best = -INFINITY; int bi = 0;
      for (int j = 0; j < ENUM; j++)
        if (!((mask >> j) & 1u) && lg[j] > best) { best = lg[j]; bi = j; }
      mask |= 1u << bi; sel[k] = bi; sv[k] = best;
    }
    float m = sv[0], den = 0.f, ex[KTOP];
    for (int k = 0; k < KTOP; k++) { ex[k] = expf(sv[k] - m); den += ex[k]; }
    for (int k = 0; k < KTOP; k++) {
      tidx[t * KTOP + k] = sel[k];
      tw[t * KTOP + k] = ex[k] / den;
      atomicAdd(&counts[sel[k]], 1);
    }
  }
}

// ---------------- scan: offsets + zero cursors ----------------
__global__ void scan_kernel(const int* __restrict__ counts, int* __restrict__ offs,
                            int* __restrict__ cur) {
  if (threadIdx.x == 0) {
    int a = 0;
    for (int e = 0; e < ENUM; e++) { offs[e] = a; a += counts[e]; }
    offs[ENUM] = a;
  }
  if (threadIdx.x < ENUM) cur[threadIdx.x] = 0;
}

// ---------------- scatter: build per-expert row lists ----------------
__global__ __launch_bounds__(256) void scatter_kernel(const int* __restrict__ tidx,
                                                      const float* __restrict__ tw,
                                                      const int* __restrict__ offs,
                                                      int* __restrict__ cur,
                                                      int* __restrict__ rtok,
                                                      float* __restrict__ rw) {
  int i = blockIdx.x * 256 + threadIdx.x;  // 0..8191
  int e = tidx[i];
  int pos = atomicAdd(&cur[e], 1);
  int row = offs[e] + pos;
  rtok[row] = i >> 2;
  rw[row] = tw[i];
}

// ---------------- GEMM1: act = silu(x Wg) * (x Wu), per expert ----------------
// BM=256, BN=64 (of I), BK=64, 512 threads (8 waves as 4x2)
__global__ __launch_bounds__(512) void gemm1_kernel(const u16* __restrict__ xb,
                                                    const float* __restrict__ wgp,
                                                    const float* __restrict__ wup,
                                                    const int* __restrict__ offs,
                                                    const int* __restrict__ rtok,
                                                    u16* __restrict__ act) {
  int d = blockIdx.x;
  int q = gridDim.x >> 3;                 // XCD-chunked swizzle (nwg % 8 == 0)
  int w = (d & 7) * q + (d >> 3);
  int nt = w % 12; int mt = (w / 12) & 7; int e = w / 96;
  int off = offs[e], cnt = offs[e + 1] - off;
  int m0 = mt << 8;
  if (m0 >= cnt) return;
  int rows = cnt - m0; if (rows > 256) rows = 256;
  int baser = off + m0;
  int n0 = nt << 6;

  __shared__ __align__(16) u16 As[256 * 64];     // XOR-swizzled, row stride 128B
  __shared__ __align__(16) u16 Bs[2][64 * 66];   // [k][n] pad 66, row stride 132B

  int tid = threadIdx.x;
  int ln = tid & 63;
  int wv = tid >> 6;
  int wm = wv >> 1, wn = wv & 1;

  int ar = tid >> 1;                       // 2 threads per A row
  int tokr = (ar < rows) ? rtok[baser + ar] : -1;
  const long e_off = (long)e * (HDIM * IDIM);

  f32x4 accg[4][2], accu[4][2];
  f32x4 zz = {0.f, 0.f, 0.f, 0.f};
#pragma unroll
  for (int a = 0; a < 4; a++)
#pragma unroll
    for (int b = 0; b < 2; b++) { accg[a][b] = zz; accu[a][b] = zz; }

  for (int k0 = 0; k0 < HDIM; k0 += 64) {
    // stage A (gathered token rows, bf16)
    {
      int kc = (tid & 1) * 32;
#pragma unroll
      for (int i = 0; i < 4; i++) {
        u16x8 v = {};
        if (tokr >= 0) v = *(const u16x8*)(xb + (long)tokr * HDIM + k0 + kc + i * 8);
        int ad = (ar * 128 + (kc + i * 8) * 2) ^ ((ar & 7) << 4);
        *(u16x8*)((char*)As + ad) = v;
      }
    }
    // stage Bg / Bu (f32 -> bf16)
#pragma unroll
    for (int i = 0; i < 2; i++) {
      int kr = (tid >> 4) + i * 32;
      int nc = (tid & 15) * 4;
      long gof = e_off + (long)(k0 + kr) * IDIM + n0 + nc;
      float4 vg = *(const float4*)(wgp + gof);
      float4 vu = *(const float4*)(wup + gof);
      char* bg = (char*)Bs[0] + kr * 132 + nc * 2;
      char* bu = (char*)Bs[1] + kr * 132 + nc * 2;
      *(unsigned*)(bg) = pk2(vg.x, vg.y);
      *(unsigned*)(bg + 4) = pk2(vg.z, vg.w);
      *(unsigned*)(bu) = pk2(vu.x, vu.y);
      *(unsigned*)(bu + 4) = pk2(vu.z, vu.w);
    }
    __syncthreads();
#pragma unroll
    for (int kk = 0; kk < 64; kk += 32) {
      int kl = kk + (ln >> 4) * 8;
      s16x8 a[4];
#pragma unroll
      for (int mf = 0; mf < 4; mf++) {
        int r = wm * 64 + mf * 16 + (ln & 15);
        int ad = (r * 128 + kl * 2) ^ ((r & 7) << 4);
        a[mf] = *(const s16x8*)((const char*)As + ad);
      }
#pragma unroll
      for (int nf = 0; nf < 2; nf++) {
        int c = wn * 32 + nf * 16 + (ln & 15);
        s16x8 bg, bu;
#pragma unroll
        for (int j = 0; j < 8; j++) {
          bg[j] = *(const short*)((const char*)Bs[0] + (kl + j) * 132 + c * 2);
          bu[j] = *(const short*)((const char*)Bs[1] + (kl + j) * 132 + c * 2);
        }
#pragma unroll
        for (int mf = 0; mf < 4; mf++) {
          accg[mf][nf] = __builtin_amdgcn_mfma_f32_16x16x32_bf16(a[mf], bg, accg[mf][nf], 0, 0, 0);
          accu[mf][nf] = __builtin_amdgcn_mfma_f32_16x16x32_bf16(a[mf], bu, accu[mf][nf], 0, 0, 0);
        }
      }
    }
    __syncthreads();
  }
  // epilogue: silu(g)*u -> bf16 act
  int rbase = wm * 64 + (ln >> 4) * 4;
  int cbase = n0 + wn * 32 + (ln & 15);
#pragma unroll
  for (int mf = 0; mf < 4; mf++) {
#pragma unroll
    for (int r4 = 0; r4 < 4; r4++) {
      int rl = rbase + mf * 16 + r4;
      if (rl < rows) {
        long rowb = (long)(baser + rl) * IDIM;
#pragma unroll
        for (int nf = 0; nf < 2; nf++) {
          float g = accg[mf][nf][r4], u = accu[mf][nf][r4];
          float av = g / (1.f + __expf(-g)) * u;
          act[rowb + cbase + nf * 16] = f2bf(av);
        }
      }
    }
  }
}

// ---------------- GEMM2: out[tok] += w * (act Wd), per expert ----------------
// BM=256, BN=64 (of H), BK=64, 512 threads
__global__ __launch_bounds__(512) void gemm2_kernel(const u16* __restrict__ act,
                                                    const float* __restrict__ wdp,
                                                    const int* __restrict__ offs,
                                                    const int* __restrict__ rtok,
                                                    const float* __restrict__ rw,
                                                    float* __restrict__ out) {
  int d = blockIdx.x;
  int q = gridDim.x >> 3;
  int w = (d & 7) * q + (d >> 3);
  int nt = w & 31; int mt = (w >> 5) & 7; int e = w >> 8;
  int off = offs[e], cnt = offs[e + 1] - off;
  int m0 = mt << 8;
  if (m0 >= cnt) return;
  int rows = cnt - m0; if (rows > 256) rows = 256;
  int baser = off + m0;
  int n0 = nt << 6;

  __shared__ __align__(16) u16 As[256 * 64];
  __shared__ __align__(16) u16 Bs[64 * 66];

  int tid = threadIdx.x;
  int ln = tid & 63;
  int wv = tid >> 6;
  int wm = wv >> 1, wn = wv & 1;
  int ar = tid >> 1;
  const long e_off = (long)e * (IDIM * HDIM);

  f32x4 acc[4][2];
  f32x4 zz = {0.f, 0.f, 0.f, 0.f};
#pragma unroll
  for (int a = 0; a < 4; a++)
#pragma unroll
    for (int b = 0; b < 2; b++) acc[a][b] = zz;

  for (int k0 = 0; k0 < IDIM; k0 += 64) {
    {
      int kc = (tid & 1) * 32;
#pragma unroll
      for (int i = 0; i < 4; i++) {
        u16x8 v = {};
        if (ar < rows) v = *(const u16x8*)(act + (long)(baser + ar) * IDIM + k0 + kc + i * 8);
        int ad = (ar * 128 + (kc + i * 8) * 2) ^ ((ar & 7) << 4);
        *(u16x8*)((char*)As + ad) = v;
      }
    }
#pragma unroll
    for (int i = 0; i < 2; i++) {
      int kr = (tid >> 4) + i * 32;
      int nc = (tid & 15) * 4;
      long gof = e_off + (long)(k0 + kr) * HDIM + n0 + nc;
      float4 vb = *(const float4*)(wdp + gof);
      char* bb = (char*)Bs + kr * 132 + nc * 2;
      *(unsigned*)(bb) = pk2(vb.x, vb.y);
      *(unsigned*)(bb + 4) = pk2(vb.z, vb.w);
    }
    __syncthreads();
#pragma unroll
    for (int kk = 0; kk < 64; kk += 32) {
      int kl = kk + (ln >> 4) * 8;
      s16x8 a[4];
#pragma unroll
      for (int mf = 0; mf < 4; mf++) {
        int r = wm * 64 + mf * 16 + (ln & 15);
        int ad = (r * 128 + kl * 2) ^ ((r & 7) << 4);
        a[mf] = *(const s16x8*)((const char*)As + ad);
      }
#pragma unroll
      for (int nf = 0; nf < 2; nf++) {
        int c = wn * 32 + nf * 16 + (ln & 15);
        s16x8 bv;
#pragma unroll
        for (int j = 0; j < 8; j++)
          bv[j] = *(const short*)((const char*)Bs + (kl + j) * 132 + c * 2);
#pragma unroll
        for (int mf = 0; mf < 4; mf++)
          acc[mf][nf] = __builtin_amdgcn_mfma_f32_16x16x32_bf16(a[mf], bv, acc[mf][nf], 0, 0, 0);
      }
    }
    __syncthreads();
  }
  // epilogue: scale by routing weight, atomic add into out
  int rbase = wm * 64 + (ln >> 4) * 4;
  int cbase = n0 + wn * 32 + (ln & 15);
#pragma unroll
  for (int mf = 0; mf < 4; mf++) {
#pragma unroll
    for (int r4 = 0; r4 < 4; r4++) {
      int rl = rbase + mf * 16 + r4;
      if (rl < rows) {
        int rr = baser + rl;
        float wt = rw[rr];
        long ob = (long)rtok[rr] * HDIM + cbase;
#pragma unroll
        for (int nf = 0; nf < 2; nf++)
          atomicAdd(&out[ob + nf * 16], acc[mf][nf][r4] * wt);
      }
    }
  }
}

extern "C" void kernel_launch(void* const* d_in, const int* in_sizes, int n_in,
                              void* d_out, int out_size, void* d_ws, size_t ws_size,
                              hipStream_t stream) {
  const float* x = (const float*)d_in[0];
  const float* gw = (const float*)d_in[1];
  const float* wgate = (const float*)d_in[2];
  const float* wup = (const float*)d_in[3];
  const float* wdown = (const float*)d_in[4];
  float* out = (float*)d_out;

  char* ws = (char*)d_ws;
  u16* xb = (u16*)(ws + WS_XB);
  u16* act = (u16*)(ws + WS_ACT);
  int* tidx = (int*)(ws + WS_TIDX);
  float* tw = (float*)(ws + WS_TW);
  int* cnt = (int*)(ws + WS_CNT);
  int* offs = (int*)(ws + WS_OFFS);
  int* cur = (int*)(ws + WS_CUR);
  int* rtok = (int*)(ws + WS_RTOK);
  float* rw = (float*)(ws + WS_RW);

  hipMemsetAsync(cnt, 0, 128, stream);
  hipMemsetAsync(d_out, 0, (size_t)out_size * sizeof(float), stream);

  hipLaunchKernelGGL(cvt_x_kernel, dim3(TTOK * HDIM / (256 * 8)), dim3(256), 0, stream, x, xb);
  hipLaunchKernelGGL(router_kernel, dim3(TTOK), dim3(256), 0, stream, x, gw, tidx, tw, cnt);
  hipLaunchKernelGGL(scan_kernel, dim3(1), dim3(64), 0, stream, cnt, offs, cur);
  hipLaunchKernelGGL(scatter_kernel, dim3(TTOK * KTOP / 256), dim3(256), 0, stream, tidx, tw, offs, cur, rtok, rw);
  hipLaunchKernelGGL(gemm1_kernel, dim3(ENUM * 8 * 12), dim3(512), 0, stream, xb, wgate, wup, offs, rtok, act);
  hipLaunchKernelGGL(gemm2_kernel, dim3(ENUM * 8 * 32), dim3(512), 0, stream, act, wdown, offs, rtok, rw, out);
}

// Round 2
// 438.846 us; speedup vs baseline: 1.1413x; 1.1413x over previous
//
#include <hip/hip_runtime.h>
#include <hip/hip_bf16.h>
#include <math.h>

typedef unsigned short u16;
typedef unsigned int u32;
typedef short s16x8 __attribute__((ext_vector_type(8)));
typedef unsigned short u16x8 __attribute__((ext_vector_type(8)));
typedef float f32x4 __attribute__((ext_vector_type(4)));

// Problem constants
#define TTOK 2048
#define HDIM 2048
#define ENUM 32
#define IDIM 768
#define KTOP 4

// Workspace layout (bytes)
#define WS_XB   0L                         // u16[2048*2048]  x in bf16       (8 MB)
#define WS_ACT  8388608L                   // u16[8192*768]   act bf16        (12.6 MB)
#define WS_TIDX 20971520L                  // int[8192] topk expert idx
#define WS_TW   (WS_TIDX + 32768L)         // float[8192] topk weights
#define WS_CNT  (WS_TW + 32768L)           // int[32] counts
#define WS_OFFS (WS_CNT + 128L)            // int[33] offsets
#define WS_CUR  (WS_OFFS + 256L)           // int[32] cursors
#define WS_RTOK (WS_CUR + 128L)            // int[8192] row -> token
#define WS_RW   (WS_RTOK + 32768L)         // float[8192] row -> routing weight

// LDS strides: rows padded to 40 u16 (80 B) -> 2-way-max bank aliasing on b128
#define LDA 40

__device__ __forceinline__ u16 f2bf(float f) {
  unsigned u = __builtin_bit_cast(unsigned, f);
  unsigned r = (u + 0x7fffu + ((u >> 16) & 1u)) >> 16;
  return (u16)r;
}
__device__ __forceinline__ unsigned pk2(float a, float b) {
  return (unsigned)f2bf(a) | ((unsigned)f2bf(b) << 16);
}

// ---------------- x f32 -> bf16 ----------------
__global__ __launch_bounds__(256) void cvt_x_kernel(const float* __restrict__ x,
                                                    u16* __restrict__ xb) {
  long i = ((long)blockIdx.x * 256 + threadIdx.x) * 8;
  float4 a = *(const float4*)(x + i);
  float4 b = *(const float4*)(x + i + 4);
  uint4 o;
  o.x = pk2(a.x, a.y);
  o.y = pk2(a.z, a.w);
  o.z = pk2(b.x, b.y);
  o.w = pk2(b.z, b.w);
  *(uint4*)(xb + i) = o;
}

// ---------------- router ----------------
__global__ __launch_bounds__(256) void router_kernel(const float* __restrict__ x,
                                                     const float* __restrict__ gw,
                                                     int* __restrict__ tidx,
                                                     float* __restrict__ tw,
                                                     int* __restrict__ counts) {
  __shared__ float xs[HDIM];
  __shared__ float part[256];
  __shared__ float lg[ENUM];
  int t = blockIdx.x;
  const float4* xr = (const float4*)(x + (long)t * HDIM);
  float4* xs4 = (float4*)xs;
  for (int i = threadIdx.x; i < HDIM / 4; i += 256) xs4[i] = xr[i];
  __syncthreads();
  int e = threadIdx.x >> 3, ch = threadIdx.x & 7;
  const float4* gp = (const float4*)(gw + (long)e * HDIM + ch * 256);
  const float4* xp = (const float4*)(xs + ch * 256);
  float s = 0.f;
#pragma unroll 8
  for (int c = 0; c < 64; c++) {
    float4 gv = gp[c], xv = xp[c];
    s += gv.x * xv.x + gv.y * xv.y + gv.z * xv.z + gv.w * xv.w;
  }
  part[threadIdx.x] = s;
  __syncthreads();
  if (threadIdx.x < 32) {
    float v = 0.f;
#pragma unroll
    for (int j = 0; j < 8; j++) v += part[threadIdx.x * 8 + j];
    lg[threadIdx.x] = v;
  }
  __syncthreads();
  if (threadIdx.x == 0) {
    int sel[KTOP]; float sv[KTOP];
    unsigned mask = 0;
    for (int k = 0; k < KTOP; k++) {
      float best = -INFINITY; int bi = 0;
      for (int j = 0; j < ENUM; j++)
        if (!((mask >> j) & 1u) && lg[j] > best) { best = lg[j]; bi = j; }
      mask |= 1u << bi; sel[k] = bi; sv[k] = best;
    }
    float m = sv[0], den = 0.f, ex[KTOP];
    for (int k = 0; k < KTOP; k++) { ex[k] = expf(sv[k] - m); den += ex[k]; }
    for (int k = 0; k < KTOP; k++) {
      tidx[t * KTOP + k] = sel[k];
      tw[t * KTOP + k] = ex[k] / den;
      atomicAdd(&counts[sel[k]], 1);
    }
  }
}

// ---------------- scan ----------------
__global__ void scan_kernel(const int* __restrict__ counts, int* __restrict__ offs,
                            int* __restrict__ cur) {
  if (threadIdx.x == 0) {
    int a = 0;
    for (int e = 0; e < ENUM; e++) { offs[e] = a; a += counts[e]; }
    offs[ENUM] = a;
  }
  if (threadIdx.x < ENUM) cur[threadIdx.x] = 0;
}

// ---------------- scatter ----------------
__global__ __launch_bounds__(256) void scatter_kernel(const int* __restrict__ tidx,
                                                      const float* __restrict__ tw,
                                                      const int* __restrict__ offs,
                                                      int* __restrict__ cur,
                                                      int* __restrict__ rtok,
                                                      float* __restrict__ rw) {
  int i = blockIdx.x * 256 + threadIdx.x;
  int e = tidx[i];
  int pos = atomicAdd(&cur[e], 1);
  int row = offs[e] + pos;
  rtok[row] = i >> 2;
  rw[row] = tw[i];
}

// ================= GEMM1: act = silu(x Wg) * (x Wu) =================
// BM=256, BN=64, BK=32, 512 threads (8 waves, 4x2). Double-buffered,
// reg-staged pipeline, B stored transposed [n][k] bf16 in LDS.
__global__ __launch_bounds__(512, 4) void gemm1_kernel(const u16* __restrict__ xb,
                                                       const float* __restrict__ wgp,
                                                       const float* __restrict__ wup,
                                                       const int* __restrict__ offs,
                                                       const int* __restrict__ rtok,
                                                       u16* __restrict__ act) {
  int d = blockIdx.x;
  int q8 = gridDim.x >> 3;
  int w = (d & 7) * q8 + (d >> 3);
  int nt = w % 12; int rem = w / 12; int mt = rem & 7; int e = rem >> 3;
  int off = offs[e], cnt = offs[e + 1] - off;
  int m0 = mt << 8;
  if (m0 >= cnt) return;
  int rows = cnt - m0; if (rows > 256) rows = 256;
  int baser = off + m0;
  int n0 = nt << 6;

  __shared__ __align__(16) u16 As[2][256 * LDA];      // 40 KB
  __shared__ __align__(16) u16 Bsm[2][2][64 * LDA];   // 20 KB

  int tid = threadIdx.x;
  int ln = tid & 63;
  int wv = tid >> 6;
  int wm = wv >> 1, wn = wv & 1;
  int lhi = ln >> 4;          // 0..3 (k chunk)
  int llo = ln & 15;

  // ---- staging assignments ----
  // A: 2 threads/row, 16 u16 each
  int ar = tid >> 1;
  int kcA = (tid & 1) * 16;
  int arow = ar < rows ? ar : rows - 1;
  const u16* aSrc = xb + (long)rtok[baser + arow] * HDIM + kcA;
  u16* aDst0 = &As[0][ar * LDA + kcA];
  u16* aDst1 = &As[1][ar * LDA + kcA];
  // B: threads 0-255 gate, 256-511 up; per thread k-rows {2q,2q+1}, 4 n's
  int half = tid >> 8;
  int t2 = tid & 255;
  int qk = t2 >> 4;            // 0..15 dword (k-pair) index
  int ncB = (t2 & 15) * 4;
  int qx = qk ^ ((t2 & 3) << 2);   // chunk-XOR on write side
  const float* bSrc = (half ? wup : wgp) + (long)e * (HDIM * IDIM) +
                      (long)(2 * qk) * IDIM + n0 + ncB;
  char* bDst0 = (char*)&Bsm[0][half][0] + qx * 4;
  char* bDst1 = (char*)&Bsm[1][half][0] + qx * 4;

  f32x4 accg[4][2], accu[4][2];
  f32x4 zz = {0.f, 0.f, 0.f, 0.f};
#pragma unroll
  for (int a = 0; a < 4; a++)
#pragma unroll
    for (int b = 0; b < 2; b++) { accg[a][b] = zz; accu[a][b] = zz; }

  u16x8 rA0, rA1;
  float4 rB0, rB1;

#define G1_LOAD(t)                                                   \
  {                                                                  \
    const u16* ap = aSrc + (t) * 32;                                 \
    rA0 = *(const u16x8*)ap;                                         \
    rA1 = *(const u16x8*)(ap + 8);                                   \
    const float* bp = bSrc + (long)(t) * 32 * IDIM;                  \
    rB0 = *(const float4*)bp;                                        \
    rB1 = *(const float4*)(bp + IDIM);                               \
  }
#define G1_WRITE(buf)                                                \
  {                                                                  \
    *(u16x8*)(buf ? aDst1 : aDst0) = rA0;                            \
    *(u16x8*)((buf ? aDst1 : aDst0) + 8) = rA1;                      \
    char* bd = buf ? bDst1 : bDst0;                                  \
    *(u32*)(bd + (ncB + 0) * 80) = pk2(rB0.x, rB1.x);                \
    *(u32*)(bd + (ncB + 1) * 80) = pk2(rB0.y, rB1.y);                \
    *(u32*)(bd + (ncB + 2) * 80) = pk2(rB0.z, rB1.z);                \
    *(u32*)(bd + (ncB + 3) * 80) = pk2(rB0.w, rB1.w);                \
  }

  const int NS = HDIM / 32;  // 64
  G1_LOAD(0);
  G1_WRITE(0);
  G1_LOAD(1);
  __syncthreads();

  for (int t = 0; t < NS; ++t) {
    int cur = t & 1;
    if (t + 1 < NS) G1_WRITE(cur ^ 1);
    if (t + 2 < NS) G1_LOAD(t + 2);
    // compute from buf[cur]
    {
      const u16* Ab = &As[cur][0];
      const u16* Bg = &Bsm[cur][0][0];
      const u16* Bu = &Bsm[cur][1][0];
      int g16 = lhi * 8;
      s16x8 a[4];
#pragma unroll
      for (int mf = 0; mf < 4; mf++) {
        int r = wm * 64 + mf * 16 + llo;
        a[mf] = *(const s16x8*)&Ab[r * LDA + g16];
      }
#pragma unroll
      for (int nf = 0; nf < 2; nf++) {
        int c = wn * 32 + nf * 16 + llo;
        int bo = c * LDA + ((lhi ^ ((c >> 2) & 3)) * 8);
        s16x8 bg = *(const s16x8*)&Bg[bo];
        s16x8 bu = *(const s16x8*)&Bu[bo];
#pragma unroll
        for (int mf = 0; mf < 4; mf++) {
          accg[mf][nf] = __builtin_amdgcn_mfma_f32_16x16x32_bf16(a[mf], bg, accg[mf][nf], 0, 0, 0);
          accu[mf][nf] = __builtin_amdgcn_mfma_f32_16x16x32_bf16(a[mf], bu, accu[mf][nf], 0, 0, 0);
        }
      }
    }
    __syncthreads();
  }

  // epilogue: silu(g)*u -> bf16 act
  int rbase = wm * 64 + lhi * 4;
  int cbase = n0 + wn * 32 + llo;
#pragma unroll
  for (int mf = 0; mf < 4; mf++) {
#pragma unroll
    for (int r4 = 0; r4 < 4; r4++) {
      int rl = rbase + mf * 16 + r4;
      if (rl < rows) {
        long rowb = (long)(baser + rl) * IDIM;
#pragma unroll
        for (int nf = 0; nf < 2; nf++) {
          float g = accg[mf][nf][r4], u = accu[mf][nf][r4];
          float av = g / (1.f + __expf(-g)) * u;
          act[rowb + cbase + nf * 16] = f2bf(av);
        }
      }
    }
  }
#undef G1_LOAD
#undef G1_WRITE
}

// ================= GEMM2: out[tok] += w * (act Wd) =================
// BM=256, BN=128, BK=32, 512 threads (8 waves, 4x2), same template.
__global__ __launch_bounds__(512, 4) void gemm2_kernel(const u16* __restrict__ act,
                                                       const float* __restrict__ wdp,
                                                       const int* __restrict__ offs,
                                                       const int* __restrict__ rtok,
                                                       const float* __restrict__ rw,
                                                       float* __restrict__ out) {
  int d = blockIdx.x;
  int q8 = gridDim.x >> 3;
  int w = (d & 7) * q8 + (d >> 3);
  int nt = w & 15; int mt = (w >> 4) & 7; int e = w >> 7;
  int off = offs[e], cnt = offs[e + 1] - off;
  int m0 = mt << 8;
  if (m0 >= cnt) return;
  int rows = cnt - m0; if (rows > 256) rows = 256;
  int baser = off + m0;
  int n0 = nt << 7;

  __shared__ __align__(16) u16 As[2][256 * LDA];     // 40 KB
  __shared__ __align__(16) u16 Bsm[2][128 * LDA];    // 20 KB

  int tid = threadIdx.x;
  int ln = tid & 63;
  int wv = tid >> 6;
  int wm = wv >> 1, wn = wv & 1;
  int lhi = ln >> 4;
  int llo = ln & 15;

  int ar = tid >> 1;
  int kcA = (tid & 1) * 16;
  int arow = ar < rows ? ar : rows - 1;
  const u16* aSrc = act + (long)(baser + arow) * IDIM + kcA;
  u16* aDst0 = &As[0][ar * LDA + kcA];
  u16* aDst1 = &As[1][ar * LDA + kcA];

  int qk = tid >> 5;            // 0..15
  int ncB = (tid & 31) * 4;     // 0..124
  int qx = qk ^ ((tid & 3) << 2);
  const float* bSrc = wdp + (long)e * (IDIM * HDIM) + (long)(2 * qk) * HDIM + n0 + ncB;
  char* bDst0 = (char*)&Bsm[0][0] + qx * 4;
  char* bDst1 = (char*)&Bsm[1][0] + qx * 4;

  f32x4 acc[4][4];
  f32x4 zz = {0.f, 0.f, 0.f, 0.f};
#pragma unroll
  for (int a = 0; a < 4; a++)
#pragma unroll
    for (int b = 0; b < 4; b++) acc[a][b] = zz;

  u16x8 rA0, rA1;
  float4 rB0, rB1;

#define G2_LOAD(t)                                                   \
  {                                                                  \
    const u16* ap = aSrc + (t) * 32;                                 \
    rA0 = *(const u16x8*)ap;                                         \
    rA1 = *(const u16x8*)(ap + 8);                                   \
    const float* bp = bSrc + (long)(t) * 32 * HDIM;                  \
    rB0 = *(const float4*)bp;                                        \
    rB1 = *(const float4*)(bp + HDIM);                               \
  }
#define G2_WRITE(buf)                                                \
  {                                                                  \
    *(u16x8*)(buf ? aDst1 : aDst0) = rA0;                            \
    *(u16x8*)((buf ? aDst1 : aDst0) + 8) = rA1;                      \
    char* bd = buf ? bDst1 : bDst0;                                  \
    *(u32*)(bd + (ncB + 0) * 80) = pk2(rB0.x, rB1.x);                \
    *(u32*)(bd + (ncB + 1) * 80) = pk2(rB0.y, rB1.y);                \
    *(u32*)(bd + (ncB + 2) * 80) = pk2(rB0.z, rB1.z);                \
    *(u32*)(bd + (ncB + 3) * 80) = pk2(rB0.w, rB1.w);                \
  }

  const int NS = IDIM / 32;  // 24
  G2_LOAD(0);
  G2_WRITE(0);
  G2_LOAD(1);
  __syncthreads();

  for (int t = 0; t < NS; ++t) {
    int cur = t & 1;
    if (t + 1 < NS) G2_WRITE(cur ^ 1);
    if (t + 2 < NS) G2_LOAD(t + 2);
    {
      const u16* Ab = &As[cur][0];
      const u16* Bb = &Bsm[cur][0];
      int g16 = lhi * 8;
      s16x8 a[4];
#pragma unroll
      for (int mf = 0; mf < 4; mf++) {
        int r = wm * 64 + mf * 16 + llo;
        a[mf] = *(const s16x8*)&Ab[r * LDA + g16];
      }
#pragma unroll
      for (int nf = 0; nf < 4; nf++) {
        int c = wn * 64 + nf * 16 + llo;
        int bo = c * LDA + ((lhi ^ ((c >> 2) & 3)) * 8);
        s16x8 bv = *(const s16x8*)&Bb[bo];
#pragma unroll
        for (int mf = 0; mf < 4; mf++)
          acc[mf][nf] = __builtin_amdgcn_mfma_f32_16x16x32_bf16(a[mf], bv, acc[mf][nf], 0, 0, 0);
      }
    }
    __syncthreads();
  }

  // epilogue
  int rbase = wm * 64 + lhi * 4;
  int cbase = n0 + wn * 64 + llo;
#pragma unroll
  for (int mf = 0; mf < 4; mf++) {
#pragma unroll
    for (int r4 = 0; r4 < 4; r4++) {
      int rl = rbase + mf * 16 + r4;
      if (rl < rows) {
        int rr = baser + rl;
        float wt = rw[rr];
        long ob = (long)rtok[rr] * HDIM + cbase;
#pragma unroll
        for (int nf = 0; nf < 4; nf++)
          atomicAdd(&out[ob + nf * 16], acc[mf][nf][r4] * wt);
      }
    }
  }
#undef G2_LOAD
#undef G2_WRITE
}

extern "C" void kernel_launch(void* const* d_in, const int* in_sizes, int n_in,
                              void* d_out, int out_size, void* d_ws, size_t ws_size,
                              hipStream_t stream) {
  const float* x = (const float*)d_in[0];
  const float* gw = (const float*)d_in[1];
  const float* wgate = (const float*)d_in[2];
  const float* wup = (const float*)d_in[3];
  const float* wdown = (const float*)d_in[4];
  float* out = (float*)d_out;

  char* ws = (char*)d_ws;
  u16* xb = (u16*)(ws + WS_XB);
  u16* act = (u16*)(ws + WS_ACT);
  int* tidx = (int*)(ws + WS_TIDX);
  float* tw = (float*)(ws + WS_TW);
  int* cnt = (int*)(ws + WS_CNT);
  int* offs = (int*)(ws + WS_OFFS);
  int* cur = (int*)(ws + WS_CUR);
  int* rtok = (int*)(ws + WS_RTOK);
  float* rw = (float*)(ws + WS_RW);

  hipMemsetAsync(cnt, 0, 128, stream);
  hipMemsetAsync(d_out, 0, (size_t)out_size * sizeof(float), stream);

  hipLaunchKernelGGL(cvt_x_kernel, dim3(TTOK * HDIM / (256 * 8)), dim3(256), 0, stream, x, xb);
  hipLaunchKernelGGL(router_kernel, dim3(TTOK), dim3(256), 0, stream, x, gw, tidx, tw, cnt);
  hipLaunchKernelGGL(scan_kernel, dim3(1), dim3(64), 0, stream, cnt, offs, cur);
  hipLaunchKernelGGL(scatter_kernel, dim3(TTOK * KTOP / 256), dim3(256), 0, stream, tidx, tw, offs, cur, rtok, rw);
  hipLaunchKernelGGL(gemm1_kernel, dim3(ENUM * 8 * 12), dim3(512), 0, stream, xb, wgate, wup, offs, rtok, act);
  hipLaunchKernelGGL(gemm2_kernel, dim3(ENUM * 8 * 16), dim3(512), 0, stream, act, wdown, offs, rtok, rw, out);
}